// Round 4
// baseline (2034.140 us; speedup 1.0000x reference)
//
#include <hip/hip_runtime.h>
#include <stdint.h>

typedef __bf16 bf16x8 __attribute__((ext_vector_type(8)));
typedef float f32x4 __attribute__((ext_vector_type(4)));
typedef unsigned short ushort8 __attribute__((ext_vector_type(8)));

#define DEV static __device__ __forceinline__

DEV float bf2f(unsigned short h) {
  union { unsigned u; float f; } v; v.u = ((unsigned)h) << 16; return v.f;
}
DEV unsigned short f2bf(float f) {
  union { float f; unsigned u; } v; v.f = f;
  unsigned r = v.u + 0x7fffu + ((v.u >> 16) & 1u);  // RNE
  return (unsigned short)(r >> 16);
}
DEV float gelu_f(float x) {  // jax.nn.gelu approximate=True (tanh)
  const float c = 0.7978845608028654f;
  return 0.5f * x * (1.f + tanhf(c * (x + 0.044715f * x * x * x)));
}

struct Scalars { int active; int step_active; int steps; float t; float dt; };

// idx width probe (int64 -> (id,0,id,0,...) viewed as int32). Proven harmless.
__global__ void detect_idx_kernel(const int* idx, int* i64f) {
  __shared__ int anyOdd, anyEven;
  if (threadIdx.x == 0) { anyOdd = 0; anyEven = 0; }
  __syncthreads();
  for (int j = threadIdx.x; j < 1024; j += 256) {
    int v = idx[j];
    if (j & 1) { if (v != 0) anyOdd = 1; }
    else       { if (v != 0) anyEven = 1; }
  }
  __syncthreads();
  if (threadIdx.x == 0) *i64f = (anyOdd == 0 && anyEven == 1) ? 1 : 0;
}

__global__ void sentinel_kernel(float* out, float val) {
  if (val != 0.f) out[0] = val;
}

// ---------------------------------------------------------------------------
// Transpose-convert: src f32, tile [ty*64..][tx*64..] of [R][C] row-major
// -> dst bf16 [n=tx*64+..][kOff + ty*64+..], optional per-k scale g[k]
// (LN gamma fold: B'[n][k] = g[k]*W[k][n]).
// ---------------------------------------------------------------------------
DEV void tr_tile2(const float* src, int ldS, unsigned short* dst, int ldD,
                  int kOff, int tx, int ty, const float* gsc, float (*lds)[65]) {
  const int tid = threadIdx.x;
#pragma unroll
  for (int jj = 0; jj < 4; ++jj) {
    int r = jj * 16 + (tid >> 4);
    int c = (tid & 15) * 4;
    float4 v = *(const float4*)&src[(size_t)(ty * 64 + r) * ldS + tx * 64 + c];
    lds[r][c] = v.x; lds[r][c + 1] = v.y; lds[r][c + 2] = v.z; lds[r][c + 3] = v.w;
  }
  __syncthreads();
  const int lr = tid >> 2, seg = (tid & 3) * 16;
  ushort8 o0, o1;
#pragma unroll
  for (int e = 0; e < 8; ++e) {
    float gs = gsc ? gsc[ty * 64 + seg + e] : 1.f;
    o0[e] = f2bf(lds[seg + e][lr] * gs);
  }
#pragma unroll
  for (int e = 0; e < 8; ++e) {
    float gs = gsc ? gsc[ty * 64 + seg + 8 + e] : 1.f;
    o1[e] = f2bf(lds[seg + 8 + e][lr] * gs);
  }
  unsigned short* dp = dst + (size_t)(tx * 64 + lr) * ldD + kOff + ty * 64 + seg;
  *(ushort8*)dp = o0;
  *(ushort8*)(dp + 8) = o1;
}

// Per-layer weight prep (one launch, 199 blocks):
//  blocks 0..47   : g1-scaled wqkv^T -> bcat rows 0..767     [n][k=256]
//  blocks 48..111 : g2-scaled w1^T   -> bcat rows 768..1791
//  blocks 112..127: wo^T -> wcat[256][1280] cols 0..255
//  blocks 128..191: w2^T -> wcat cols 256..1279
//  blocks 192..198: folded biases biasf[1792] (b_ln @ W [+ b1])
// Block 0 thread 0 also resets ODE scalars for the upcoming block.
__global__ __launch_bounds__(256) void tr_weights_kernel(
    const float* wqkv, const float* wo, const float* w1, const float* w2,
    const float* g1, const float* b1ln, const float* g2, const float* b2ln,
    const float* b1mlp, unsigned short* bcat, unsigned short* wcat,
    float* biasf, Scalars* sc) {
  int t = blockIdx.x;
  if (t == 0 && threadIdx.x == 0) {
    sc->active = 1; sc->step_active = 0; sc->t = 0.f; sc->steps = 0; sc->dt = 0.f;
  }
  if (t >= 192) {
    int n = (t - 192) * 256 + threadIdx.x;  // 0..1791
    float acc = 0.f;
    if (n < 768) {
      for (int k = 0; k < 256; ++k) acc += b1ln[k] * wqkv[(size_t)k * 768 + n];
    } else {
      int mc = n - 768;
      acc = b1mlp[mc];
      for (int k = 0; k < 256; ++k) acc += b2ln[k] * w1[(size_t)k * 1024 + mc];
    }
    biasf[n] = acc;
    return;
  }
  __shared__ float lds[64][65];
  if (t < 48) {
    tr_tile2(wqkv, 768, bcat, 256, 0, t % 12, t / 12, g1, lds);
  } else if (t < 112) {
    int u = t - 48;
    tr_tile2(w1, 1024, bcat + 768 * 256, 256, 0, u % 16, u / 16, g2, lds);
  } else if (t < 128) {
    int u = t - 112;
    tr_tile2(wo, 256, wcat, 1280, 0, u % 4, u / 4, nullptr, lds);
  } else {
    int u = t - 128;
    tr_tile2(w2, 256, wcat, 1280, 256, u % 4, u / 4, nullptr, lds);
  }
}

// ehead[i] f32 [256][16384] -> bheadT bf16 [16384][256] (into Sbuf).
__global__ __launch_bounds__(256) void tr_mat_kernel(const float* src,
                                                     unsigned short* dst) {
  __shared__ float lds[64][65];
  tr_tile2(src, 16384, dst, 256, 0, blockIdx.x, blockIdx.y, nullptr, lds);
}

// ---------------------------------------------------------------------------
// MFMA bf16 GEMM: C[1024 x N] = A[1024 x K] * B^T. 64x64 tiles, 4 waves x
// (2x2 16x16x32 frags). A bf16 [M,K]; B bf16 [N,K].
//   A-frag A[m=lane&15][k=quad*8+j]; B-frag B[k=quad*8+j][n=lane&15]
//   C/D: col=lane&15, row=quad*4+reg
// ---------------------------------------------------------------------------
enum { EPI_FUSED1 = 0, EPI_ADD2, EPI_COND_F32 };

struct GemmArgs {
  const unsigned short* A; int lda;
  const unsigned short* B; int ldb;
  void* C; int ldc;
  int K;
  const float* biasf;    // FUSED1: [1792] folded; ADD2: b2 (pre-offset)
  unsigned short* qkvb;  // FUSED1
  unsigned short* VT;    // FUSED1: [4][64][1024]
  unsigned short* af;    // FUSED1: hmid region of af[1024][1280]
  float* normsq;         // ADD2
  const int* exited;     // COND
  const int* guard;
  int xcdswz;
};

template <int EPI>
__global__ __launch_bounds__(256) void gemm_mfma(GemmArgs g) {
  if (g.guard && *g.guard == 0) return;
  int bx = blockIdx.x, by = blockIdx.y;
  if (g.xcdswz) {
    int lin = bx + gridDim.x * by;
    int cpx = (gridDim.x * gridDim.y) >> 3;
    int s2 = (lin & 7) * cpx + (lin >> 3);  // bijective: blocks % 8 == 0
    bx = s2 % gridDim.x; by = s2 / gridDim.x;
  }
  const int bm = bx * 64;
  const int bn = by * 64;

  __shared__ __align__(16) unsigned short As[64][40];  // [m][k], 80B row
  __shared__ __align__(16) unsigned short Bs[64][40];  // [n][k]

  const int tid = threadIdx.x;
  const int lane = tid & 63;
  const int wave = tid >> 6;
  const int quad = lane >> 4, l16 = lane & 15;
  const int wr = (wave >> 1) * 32, wc = (wave & 1) * 32;
  const int rowA = tid >> 2, segA = (tid & 3) * 8;  // 64 rows x 32 k

  f32x4 acc[2][2] = {};

  for (int k0 = 0; k0 < g.K; k0 += 32) {
    *(ushort8*)&As[rowA][segA] =
        *(const ushort8*)(g.A + (size_t)(bm + rowA) * g.lda + k0 + segA);
    *(ushort8*)&Bs[rowA][segA] =
        *(const ushort8*)(g.B + (size_t)(bn + rowA) * g.ldb + k0 + segA);
    __syncthreads();

    bf16x8 a0 = *(const bf16x8*)&As[wr + l16][quad * 8];
    bf16x8 a1 = *(const bf16x8*)&As[wr + 16 + l16][quad * 8];
    bf16x8 b0 = *(const bf16x8*)&Bs[wc + l16][quad * 8];
    bf16x8 b1 = *(const bf16x8*)&Bs[wc + 16 + l16][quad * 8];
    acc[0][0] = __builtin_amdgcn_mfma_f32_16x16x32_bf16(a0, b0, acc[0][0], 0, 0, 0);
    acc[0][1] = __builtin_amdgcn_mfma_f32_16x16x32_bf16(a0, b1, acc[0][1], 0, 0, 0);
    acc[1][0] = __builtin_amdgcn_mfma_f32_16x16x32_bf16(a1, b0, acc[1][0], 0, 0, 0);
    acc[1][1] = __builtin_amdgcn_mfma_f32_16x16x32_bf16(a1, b1, acc[1][1], 0, 0, 0);
    __syncthreads();
  }

  if constexpr (EPI == EPI_ADD2) {
    // dz = [O|hmid]@wcat^T + b2; fused per-row sum-of-squares
#pragma unroll
    for (int i2 = 0; i2 < 2; ++i2) {
#pragma unroll
      for (int r = 0; r < 4; ++r) {
        int row = bm + wr + i2 * 16 + quad * 4 + r;
        float sq = 0.f;
#pragma unroll
        for (int j = 0; j < 2; ++j) {
          int col = bn + wc + j * 16 + l16;
          float val = acc[i2][j][r] + g.biasf[col];
          ((float*)g.C)[(size_t)row * g.ldc + col] = val;
          sq += val * val;
        }
        sq += __shfl_xor(sq, 1); sq += __shfl_xor(sq, 2);
        sq += __shfl_xor(sq, 4); sq += __shfl_xor(sq, 8);
        if (l16 == 0) atomicAdd(g.normsq + row, sq);
      }
    }
    return;
  }

#pragma unroll
  for (int i = 0; i < 2; ++i) {
#pragma unroll
    for (int j = 0; j < 2; ++j) {
#pragma unroll
      for (int r = 0; r < 4; ++r) {
        int row = bm + wr + i * 16 + quad * 4 + r;
        int col = bn + wc + j * 16 + l16;
        float val = acc[i][j][r];
        if constexpr (EPI == EPI_FUSED1) {
          val += g.biasf[col];
          if (col < 768) {  // qkv (block-uniform: tile 64 | 768)
            unsigned short bv = f2bf(val);
            g.qkvb[(size_t)row * 768 + col] = bv;
            if (col >= 512) {  // V also transposed: VT[h][hd][tok]
              int cc = col - 512;
              g.VT[((cc >> 6) << 16) + ((cc & 63) << 10) + row] = bv;
            }
          } else {  // mlp mid: gelu -> af cols 256..1279
            g.af[(size_t)row * 1280 + 256 + (col - 768)] = f2bf(gelu_f(val));
          }
        } else if constexpr (EPI == EPI_COND_F32) {
          if (!g.exited[row])
            ((float*)g.C)[(size_t)row * g.ldc + col] = val;
        }
      }
    }
  }
}

// ---------------------------------------------------------------------------
// Fused attention: per block = (q-tile 64 rows, head). Phase1: S tiles ->
// Sbuf global (same bits as the old scores GEMM). Phase2: per-wave row
// softmax in place. Phase3: PV from Sbuf/VT -> af cols h*64..h*64+63.
// Block-local global RAW via threadfence_block + barrier.
// ---------------------------------------------------------------------------
__global__ __launch_bounds__(256) void attn_kernel(
    const unsigned short* qkvb, const unsigned short* VT,
    unsigned short* Sbuf, unsigned short* af, const int* guard) {
  if (*guard == 0) return;
  const int qt = blockIdx.x, h = blockIdx.y;
  __shared__ __align__(16) unsigned short Kb[64][72];  // 144B row (16B-mult)
  __shared__ __align__(16) unsigned short Vb[64][72];
  const int tid = threadIdx.x, lane = tid & 63, wave = tid >> 6;
  const int quad = lane >> 4, l16 = lane & 15;
  const int wr = (wave >> 1) * 32, wc = (wave & 1) * 32;
  const int srow = tid >> 3, scol = (tid & 7) * 8;  // staging: 32 rows/pass

  unsigned short* Sh = Sbuf + ((size_t)h << 20);
  const int kLim = (qt + 1) * 64;

  // stage Q tile, hoist A-frags to registers, then reuse Kb for K tiles
  {
    const unsigned short* Qp = qkvb + (size_t)(qt * 64) * 768 + h * 64;
#pragma unroll
    for (int hh = 0; hh < 2; ++hh)
      *(ushort8*)&Kb[hh * 32 + srow][scol] =
          *(const ushort8*)(Qp + (size_t)(hh * 32 + srow) * 768 + scol);
  }
  __syncthreads();
  bf16x8 aq[2][2];
#pragma unroll
  for (int k0 = 0; k0 < 2; ++k0)
#pragma unroll
    for (int ih = 0; ih < 2; ++ih)
      aq[k0][ih] = *(const bf16x8*)&Kb[wr + ih * 16 + l16][k0 * 32 + quad * 8];
  __syncthreads();

  // ---- phase 1: S = Q@K^T * 0.125, causal, bf16 -> Sbuf
  for (int kt = 0; kt <= qt; ++kt) {
    const unsigned short* Kp = qkvb + (size_t)(kt * 64) * 768 + 256 + h * 64;
#pragma unroll
    for (int hh = 0; hh < 2; ++hh)
      *(ushort8*)&Kb[hh * 32 + srow][scol] =
          *(const ushort8*)(Kp + (size_t)(hh * 32 + srow) * 768 + scol);
    __syncthreads();
    f32x4 s2[2][2] = {};
#pragma unroll
    for (int k0 = 0; k0 < 2; ++k0) {
      bf16x8 b0 = *(const bf16x8*)&Kb[wc + l16][k0 * 32 + quad * 8];
      bf16x8 b1 = *(const bf16x8*)&Kb[wc + 16 + l16][k0 * 32 + quad * 8];
      s2[0][0] = __builtin_amdgcn_mfma_f32_16x16x32_bf16(aq[k0][0], b0, s2[0][0], 0, 0, 0);
      s2[0][1] = __builtin_amdgcn_mfma_f32_16x16x32_bf16(aq[k0][0], b1, s2[0][1], 0, 0, 0);
      s2[1][0] = __builtin_amdgcn_mfma_f32_16x16x32_bf16(aq[k0][1], b0, s2[1][0], 0, 0, 0);
      s2[1][1] = __builtin_amdgcn_mfma_f32_16x16x32_bf16(aq[k0][1], b1, s2[1][1], 0, 0, 0);
    }
#pragma unroll
    for (int i = 0; i < 2; ++i)
#pragma unroll
      for (int j = 0; j < 2; ++j)
#pragma unroll
        for (int r = 0; r < 4; ++r) {
          int row = qt * 64 + wr + i * 16 + quad * 4 + r;
          int col = kt * 64 + wc + j * 16 + l16;
          float o = (col <= row) ? s2[i][j][r] * 0.125f : -1e9f;
          Sh[((size_t)row << 10) + col] = f2bf(o);
        }
    __syncthreads();
  }
  __threadfence_block();
  __syncthreads();

  // ---- phase 2: softmax rows in place (one row per wave per iteration)
  for (int rr = 0; rr < 16; ++rr) {
    int row = qt * 64 + wave * 16 + rr;
    unsigned short* p = Sh + ((size_t)row << 10);
    float v[16];
    float m = -1e30f;
#pragma unroll
    for (int ps = 0; ps < 4; ++ps) {
      int c = ps * 256 + lane * 4;
      if (c < kLim) {
        ushort4 u = *(const ushort4*)(p + c);
        v[ps * 4 + 0] = bf2f(u.x); v[ps * 4 + 1] = bf2f(u.y);
        v[ps * 4 + 2] = bf2f(u.z); v[ps * 4 + 3] = bf2f(u.w);
      } else {
        v[ps * 4 + 0] = v[ps * 4 + 1] = v[ps * 4 + 2] = v[ps * 4 + 3] = -1e30f;
      }
      m = fmaxf(m, fmaxf(fmaxf(v[ps * 4], v[ps * 4 + 1]),
                         fmaxf(v[ps * 4 + 2], v[ps * 4 + 3])));
    }
#pragma unroll
    for (int o = 32; o; o >>= 1) m = fmaxf(m, __shfl_xor(m, o));
    float s = 0.f;
#pragma unroll
    for (int e = 0; e < 16; ++e) { v[e] = expf(v[e] - m); s += v[e]; }
#pragma unroll
    for (int o = 32; o; o >>= 1) s += __shfl_xor(s, o);
    float inv = 1.f / s;
#pragma unroll
    for (int ps = 0; ps < 4; ++ps) {
      int c = ps * 256 + lane * 4;
      if (c < kLim) {
        ushort4 w4;
        w4.x = f2bf(v[ps * 4 + 0] * inv); w4.y = f2bf(v[ps * 4 + 1] * inv);
        w4.z = f2bf(v[ps * 4 + 2] * inv); w4.w = f2bf(v[ps * 4 + 3] * inv);
        *(ushort4*)(p + c) = w4;
      }
    }
  }
  __threadfence_block();
  __syncthreads();

  // ---- phase 3: O = P@V -> af cols h*64..
  f32x4 ao[2][2] = {};
  for (int kt = 0; kt <= qt; ++kt) {
    const unsigned short* Vp = VT + ((size_t)h << 16) + kt * 64;
#pragma unroll
    for (int hh = 0; hh < 2; ++hh)
      *(ushort8*)&Vb[hh * 32 + srow][scol] =
          *(const ushort8*)(Vp + (size_t)(hh * 32 + srow) * 1024 + scol);
    __syncthreads();
#pragma unroll
    for (int k0 = 0; k0 < 2; ++k0) {
      const unsigned short* pr =
          Sh + ((size_t)(qt * 64 + wr + l16) << 10) + kt * 64 + k0 * 32 + quad * 8;
      bf16x8 pa0 = *(const bf16x8*)pr;
      bf16x8 pa1 = *(const bf16x8*)(pr + (16 << 10));
      bf16x8 b0 = *(const bf16x8*)&Vb[wc + l16][k0 * 32 + quad * 8];
      bf16x8 b1 = *(const bf16x8*)&Vb[wc + 16 + l16][k0 * 32 + quad * 8];
      ao[0][0] = __builtin_amdgcn_mfma_f32_16x16x32_bf16(pa0, b0, ao[0][0], 0, 0, 0);
      ao[0][1] = __builtin_amdgcn_mfma_f32_16x16x32_bf16(pa0, b1, ao[0][1], 0, 0, 0);
      ao[1][0] = __builtin_amdgcn_mfma_f32_16x16x32_bf16(pa1, b0, ao[1][0], 0, 0, 0);
      ao[1][1] = __builtin_amdgcn_mfma_f32_16x16x32_bf16(pa1, b1, ao[1][1], 0, 0, 0);
    }
    __syncthreads();
  }
#pragma unroll
  for (int i = 0; i < 2; ++i)
#pragma unroll
    for (int j = 0; j < 2; ++j)
#pragma unroll
      for (int r = 0; r < 4; ++r) {
        int row = qt * 64 + wr + i * 16 + quad * 4 + r;
        int col = h * 64 + wc + j * 16 + l16;
        af[(size_t)row * 1280 + col] = f2bf(ao[i][j][r]);
      }
}

// ---------------------------------------------------------------------------
// Small kernels
// ---------------------------------------------------------------------------
__global__ void embed_kernel(const float* wte, const float* wpe, const int* idx,
                             float* z_prev, float* z_s, int* exited,
                             const int* i64f, Scalars* sc) {
  int tok = blockIdx.x, d = threadIdx.x;
  int id = (*i64f) ? idx[2 * tok] : idx[tok];
  float v = wte[(size_t)id * 256 + d] + wpe[(size_t)tok * 256 + d];
  z_prev[tok * 256 + d] = v;
  z_s[tok * 256 + d] = v;
  if (d == 0) exited[tok] = 0;
  if (tok == 0 && d == 0) {
    sc->active = 1; sc->step_active = 0; sc->t = 0.f; sc->steps = 0; sc->dt = 0.f;
  }
}

// Fused step head: apply pending Euler update, then plain layernorm (gamma/
// beta folded into weights) -> x_hat bf16. Also zeroes normsq.
__global__ void upln_kernel(float* z_s, const float* dz, unsigned short* xh,
                            float* normsq, const Scalars* sc) {
  const int sa = sc->step_active, act = sc->active;
  if (!sa && !act) return;
  int wave = threadIdx.x >> 6, lane = threadIdx.x & 63;
  int tok = blockIdx.x * 4 + wave;
  float* p = z_s + (size_t)tok * 256;
  float v[4];
#pragma unroll
  for (int j = 0; j < 4; ++j) v[j] = p[lane + 64 * j];
  if (sa) {
    float dt = sc->dt;
    const float* d = dz + (size_t)tok * 256;
#pragma unroll
    for (int j = 0; j < 4; ++j) {
      v[j] += dt * d[lane + 64 * j];
      p[lane + 64 * j] = v[j];
    }
  }
  if (!act) return;
  if (blockIdx.x == 0) {
#pragma unroll
    for (int j = 0; j < 4; ++j) normsq[threadIdx.x * 4 + j] = 0.f;
  }
  float s = 0.f, s2 = 0.f;
#pragma unroll
  for (int j = 0; j < 4; ++j) { s += v[j]; s2 += v[j] * v[j]; }
#pragma unroll
  for (int o = 1; o < 64; o <<= 1) { s += __shfl_xor(s, o); s2 += __shfl_xor(s2, o); }
  float mean = s * (1.f / 256.f);
  float var = s2 * (1.f / 256.f) - mean * mean;
  float rstd = rsqrtf(var + 1e-5f);
#pragma unroll
  for (int j = 0; j < 4; ++j) {
    int d = lane + 64 * j;
    xh[(size_t)tok * 256 + d] = f2bf((v[j] - mean) * rstd);
  }
}

// layernorm (exit-head): f32 in -> bf16 out, one wave per token
__global__ void ln_kernel(const float* x, const float* gg, const float* bb, int goff,
                          unsigned short* out) {
  int wave = threadIdx.x >> 6, lane = threadIdx.x & 63;
  int tok = blockIdx.x * 4 + wave;
  const float* p = x + (size_t)tok * 256;
  float v[4];
  float s = 0.f, s2 = 0.f;
#pragma unroll
  for (int j = 0; j < 4; ++j) { v[j] = p[lane + 64 * j]; s += v[j]; s2 += v[j] * v[j]; }
#pragma unroll
  for (int o = 1; o < 64; o <<= 1) { s += __shfl_xor(s, o); s2 += __shfl_xor(s2, o); }
  float mean = s * (1.f / 256.f);
  float var = s2 * (1.f / 256.f) - mean * mean;
  float rstd = rsqrtf(var + 1e-5f);
#pragma unroll
  for (int j = 0; j < 4; ++j) {
    int d = lane + 64 * j;
    out[(size_t)tok * 256 + d] = f2bf((v[j] - mean) * rstd * gg[goff + d] + bb[goff + d]);
  }
}

__global__ __launch_bounds__(1024) void scalar_kernel(const float* normsq, Scalars* sc) {
  __shared__ float red[1024];
  if (sc->active == 0) { if (threadIdx.x == 0) sc->step_active = 0; return; }
  int t = threadIdx.x;
  red[t] = sqrtf(normsq[t]);
  __syncthreads();
  for (int o = 512; o; o >>= 1) { if (t < o) red[t] += red[t + o]; __syncthreads(); }
  if (t == 0) {
    float mc = red[0] * (1.f / 1024.f);
    float scale = fminf(fmaxf(1.f / (1.f + mc), 0.5f), 2.f);
    float dt = fminf(0.5f * scale, 1.f - sc->t);  // dt_base = 1/MIN_STEPS
    sc->dt = dt;
    sc->step_active = 1;
    float tn = sc->t + dt;
    int steps = sc->steps + 1;
    sc->t = tn;
    sc->steps = steps;
    int conv = (dt * mc < 0.1f) && (steps >= 2);  // ||z_new-z|| = dt*||dz||
    sc->active = ((tn < 1.f - 1e-6f) && !conv) ? 1 : 0;
  }
}

// combine (z_prev += solver state, masked by exited) fused with next-layer
// solver-state init. Applies the final pending Euler update first.
__global__ void combine_init_kernel(float* z_prev, float* z_s, const float* dz,
                                    const int* exited, const Scalars* sc) {
  int i = blockIdx.x * 256 + threadIdx.x;
  int tok = i >> 6;
  float4 b = ((float4*)z_s)[i];
  if (sc->step_active) {
    float dt = sc->dt;
    float4 d = ((const float4*)dz)[i];
    b.x += dt * d.x; b.y += dt * d.y; b.z += dt * d.z; b.w += dt * d.w;
  }
  float4 a = ((float4*)z_prev)[i];
  if (!exited[tok]) {
    a.x += b.x; a.y += b.y; a.z += b.z; a.w += b.w;
    ((float4*)z_prev)[i] = a;
  }
  ((float4*)z_s)[i] = a;
}

__global__ __launch_bounds__(256) void conf_kernel(const float* logits, int* exited) {
  int tok = blockIdx.x;
  if (exited[tok]) return;
  const float* p = logits + ((size_t)tok << 14);
  int t = threadIdx.x, lane = t & 63, wave = t >> 6;
  float m = -1e30f;
  const float4* p4 = (const float4*)p;
  for (int j = t; j < 4096; j += 256) {
    float4 u = p4[j];
    m = fmaxf(fmaxf(fmaxf(m, u.x), u.y), fmaxf(u.z, u.w));
  }
#pragma unroll
  for (int o = 32; o; o >>= 1) m = fmaxf(m, __shfl_xor(m, o));
  __shared__ float red[4];
  if (lane == 0) red[wave] = m;
  __syncthreads();
  m = fmaxf(fmaxf(red[0], red[1]), fmaxf(red[2], red[3]));
  float s = 0.f;
  for (int j = t; j < 16384; j += 256) s += expf(p[j] - m);
#pragma unroll
  for (int o = 32; o; o >>= 1) s += __shfl_xor(s, o);
  __syncthreads();
  if (lane == 0) red[wave] = s;
  __syncthreads();
  s = red[0] + red[1] + red[2] + red[3];
  if (t == 0 && (1.f / s) > 0.9f) exited[tok] = 1;
}

// ---------------------------------------------------------------------------
// Host launch
// ---------------------------------------------------------------------------
extern "C" void kernel_launch(void* const* d_in, const int* in_sizes, int n_in,
                              void* d_out, int out_size, void* d_ws, size_t ws_size,
                              hipStream_t stream) {
  (void)out_size;
  const float* wte   = (const float*)d_in[0];
  const float* wpe   = (const float*)d_in[1];
  const float* ln1_g = (const float*)d_in[2];
  const float* ln1_b = (const float*)d_in[3];
  const float* wqkv  = (const float*)d_in[4];
  const float* wo    = (const float*)d_in[5];
  const float* ln2_g = (const float*)d_in[6];
  const float* ln2_b = (const float*)d_in[7];
  const float* w1    = (const float*)d_in[8];
  const float* b1    = (const float*)d_in[9];
  const float* w2    = (const float*)d_in[10];
  const float* b2    = (const float*)d_in[11];
  const float* eln_g = (const float*)d_in[12];
  const float* eln_b = (const float*)d_in[13];
  const float* ehead = (const float*)d_in[14];
  const int* idx = (const int*)d_in[15];
  float* out = (float*)d_out;  // f32 output

  float sentinel = 0.f;
  if (!(n_in == 16 && in_sizes[0] == 4194304 && in_sizes[14] == 16777216 &&
        in_sizes[15] == 1024))
    sentinel += 1000.f;
  if (ws_size < (size_t)20000000) sentinel += 2000.f;

  char* w = (char*)d_ws;
  auto alloc = [&](size_t bytes) {
    char* p = w; w += (bytes + 255) & ~(size_t)255; return p;
  };
  int* i64f        = (int*)alloc(256);
  Scalars* sc      = (Scalars*)alloc(sizeof(Scalars));
  int* exited      = (int*)alloc(1024 * 4);
  float* normsq    = (float*)alloc(1024 * 4);
  float* biasf     = (float*)alloc(1792 * 4);
  float* z_prev    = (float*)alloc(1024 * 256 * 4);
  float* z_s       = (float*)alloc(1024 * 256 * 4);
  float* dz        = (float*)alloc(1024 * 256 * 4);
  unsigned short* xh   = (unsigned short*)alloc(1024 * 256 * 2);
  unsigned short* zn   = (unsigned short*)alloc(1024 * 256 * 2);
  unsigned short* qkvb = (unsigned short*)alloc((size_t)1024 * 768 * 2);
  unsigned short* af   = (unsigned short*)alloc((size_t)1024 * 1280 * 2);  // [O|hmid]
  unsigned short* Sbuf = (unsigned short*)alloc((size_t)4 * 1024 * 1024 * 2);  // 8 MB (S / bheadT)
  unsigned short* bcat = (unsigned short*)alloc((size_t)1792 * 256 * 2);   // [qkvT;w1T]
  unsigned short* wcat = (unsigned short*)alloc((size_t)256 * 1280 * 2);   // [woT|w2T]
  unsigned short* VT   = (unsigned short*)alloc((size_t)4 * 64 * 1024 * 2);
  const int* guard = &sc->active;

  detect_idx_kernel<<<1, 256, 0, stream>>>(idx, i64f);
  embed_kernel<<<1024, 256, 0, stream>>>(wte, wpe, idx, z_prev, z_s, exited,
                                         i64f, sc);

  for (int i = 0; i < 4; ++i) {
    tr_weights_kernel<<<199, 256, 0, stream>>>(
        wqkv + (size_t)i * 196608, wo + (size_t)i * 65536,
        w1 + (size_t)i * 262144, w2 + (size_t)i * 262144,
        ln1_g + i * 256, ln1_b + i * 256, ln2_g + i * 256, ln2_b + i * 256,
        b1 + i * 1024, bcat, wcat, biasf, sc);
    for (int s = 0; s < 4; ++s) {
      upln_kernel<<<256, 256, 0, stream>>>(z_s, dz, xh, normsq, sc);
      {  // [qkv | gelu-mlp-mid] = xh @ bcat^T (+folded bias), N=1792
        GemmArgs a{}; a.A = xh; a.lda = 256;
        a.B = bcat; a.ldb = 256; a.K = 256;
        a.biasf = biasf; a.qkvb = qkvb; a.VT = VT; a.af = af; a.guard = guard;
        gemm_mfma<EPI_FUSED1><<<dim3(16, 28, 1), 256, 0, stream>>>(a);
      }
      attn_kernel<<<dim3(16, 4), 256, 0, stream>>>(qkvb, VT, Sbuf, af, guard);
      {  // dz = [O|hmid] @ wcat^T + b2; fused row-norm accumulation
        GemmArgs a{}; a.A = af; a.lda = 1280;
        a.B = wcat; a.ldb = 1280;
        a.C = dz; a.ldc = 256; a.K = 1280;
        a.biasf = b2 + i * 256; a.normsq = normsq; a.guard = guard;
        gemm_mfma<EPI_ADD2><<<dim3(16, 4, 1), 256, 0, stream>>>(a);
      }
      scalar_kernel<<<1, 1024, 0, stream>>>(normsq, sc);
    }
    combine_init_kernel<<<256, 256, 0, stream>>>(z_prev, z_s, dz, exited, sc);
    // Layer 0 logits are provably dead (exited all-false until after layer-1
    // conf -> layer 1 overwrites every row). i=3 conf mutates dead state.
    if (i >= 1) {
      ln_kernel<<<256, 256, 0, stream>>>(z_prev, eln_g, eln_b, i * 256, zn);
      tr_mat_kernel<<<dim3(256, 4), 256, 0, stream>>>(
          ehead + (size_t)i * 4194304, Sbuf);
      {  // blk_logits = zn @ bheadT -> d_out (f32) where !exited
        GemmArgs a{}; a.A = zn; a.lda = 256;
        a.B = Sbuf; a.ldb = 256;
        a.C = out; a.ldc = 16384; a.K = 256; a.exited = exited; a.xcdswz = 1;
        gemm_mfma<EPI_COND_F32><<<dim3(16, 256, 1), 256, 0, stream>>>(a);
      }
      if (i < 3) conf_kernel<<<1024, 256, 0, stream>>>(out, exited);
    }
  }

  sentinel_kernel<<<1, 1, 0, stream>>>(out, sentinel);
}

// Round 5
// 1501.626 us; speedup vs baseline: 1.3546x; 1.3546x over previous
//
#include <hip/hip_runtime.h>
#include <stdint.h>

typedef __bf16 bf16x8 __attribute__((ext_vector_type(8)));
typedef float f32x4 __attribute__((ext_vector_type(4)));
typedef unsigned short ushort8 __attribute__((ext_vector_type(8)));

#define DEV static __device__ __forceinline__

DEV float bf2f(unsigned short h) {
  union { unsigned u; float f; } v; v.u = ((unsigned)h) << 16; return v.f;
}
DEV unsigned short f2bf(float f) {
  union { float f; unsigned u; } v; v.f = f;
  unsigned r = v.u + 0x7fffu + ((v.u >> 16) & 1u);  // RNE
  return (unsigned short)(r >> 16);
}
DEV float gelu_f(float x) {  // jax.nn.gelu approximate=True (tanh)
  const float c = 0.7978845608028654f;
  return 0.5f * x * (1.f + tanhf(c * (x + 0.044715f * x * x * x)));
}

struct Scalars { int active; int step_active; int steps; float t; float dt; };

// idx width probe (int64 -> (id,0,id,0,...) viewed as int32). Proven harmless.
__global__ void detect_idx_kernel(const int* idx, int* i64f) {
  __shared__ int anyOdd, anyEven;
  if (threadIdx.x == 0) { anyOdd = 0; anyEven = 0; }
  __syncthreads();
  for (int j = threadIdx.x; j < 1024; j += 256) {
    int v = idx[j];
    if (j & 1) { if (v != 0) anyOdd = 1; }
    else       { if (v != 0) anyEven = 1; }
  }
  __syncthreads();
  if (threadIdx.x == 0) *i64f = (anyOdd == 0 && anyEven == 1) ? 1 : 0;
}

__global__ void sentinel_kernel(float* out, float val) {
  if (val != 0.f) out[0] = val;
}

// ---------------------------------------------------------------------------
// Transpose-convert: src f32, tile [ty*64..][tx*64..] of [R][C] row-major
// -> dst bf16 [n=tx*64+..][kOff + ty*64+..], optional per-k scale g[k]
// (LN gamma fold: B'[n][k] = g[k]*W[k][n]; identity here since g==1).
// ---------------------------------------------------------------------------
DEV void tr_tile2(const float* src, int ldS, unsigned short* dst, int ldD,
                  int kOff, int tx, int ty, const float* gsc, float (*lds)[65]) {
  const int tid = threadIdx.x;
#pragma unroll
  for (int jj = 0; jj < 4; ++jj) {
    int r = jj * 16 + (tid >> 4);
    int c = (tid & 15) * 4;
    float4 v = *(const float4*)&src[(size_t)(ty * 64 + r) * ldS + tx * 64 + c];
    lds[r][c] = v.x; lds[r][c + 1] = v.y; lds[r][c + 2] = v.z; lds[r][c + 3] = v.w;
  }
  __syncthreads();
  const int lr = tid >> 2, seg = (tid & 3) * 16;
  ushort8 o0, o1;
#pragma unroll
  for (int e = 0; e < 8; ++e) {
    float gs = gsc ? gsc[ty * 64 + seg + e] : 1.f;
    o0[e] = f2bf(lds[seg + e][lr] * gs);
  }
#pragma unroll
  for (int e = 0; e < 8; ++e) {
    float gs = gsc ? gsc[ty * 64 + seg + 8 + e] : 1.f;
    o1[e] = f2bf(lds[seg + 8 + e][lr] * gs);
  }
  unsigned short* dp = dst + (size_t)(tx * 64 + lr) * ldD + kOff + ty * 64 + seg;
  *(ushort8*)dp = o0;
  *(ushort8*)(dp + 8) = o1;
}

// Per-layer weight prep (one launch, 199 blocks):
//  blocks 0..47   : g1-scaled wqkv^T -> bcat rows 0..767     [n][k=256]
//  blocks 48..111 : g2-scaled w1^T   -> bcat rows 768..1791
//  blocks 112..127: wo^T -> wcat[256][1280] cols 0..255
//  blocks 128..191: w2^T -> wcat cols 256..1279
//  blocks 192..198: folded biases biasf[1792] (b_ln @ W [+ b1])
// Block 0 thread 0 also resets ODE scalars for the upcoming block.
__global__ __launch_bounds__(256) void tr_weights_kernel(
    const float* wqkv, const float* wo, const float* w1, const float* w2,
    const float* g1, const float* b1ln, const float* g2, const float* b2ln,
    const float* b1mlp, unsigned short* bcat, unsigned short* wcat,
    float* biasf, Scalars* sc) {
  int t = blockIdx.x;
  if (t == 0 && threadIdx.x == 0) {
    sc->active = 1; sc->step_active = 0; sc->t = 0.f; sc->steps = 0; sc->dt = 0.f;
  }
  if (t >= 192) {
    int n = (t - 192) * 256 + threadIdx.x;  // 0..1791
    float acc = 0.f;
    if (n < 768) {
      for (int k = 0; k < 256; ++k) acc += b1ln[k] * wqkv[(size_t)k * 768 + n];
    } else {
      int mc = n - 768;
      acc = b1mlp[mc];
      for (int k = 0; k < 256; ++k) acc += b2ln[k] * w1[(size_t)k * 1024 + mc];
    }
    biasf[n] = acc;
    return;
  }
  __shared__ float lds[64][65];
  if (t < 48) {
    tr_tile2(wqkv, 768, bcat, 256, 0, t % 12, t / 12, g1, lds);
  } else if (t < 112) {
    int u = t - 48;
    tr_tile2(w1, 1024, bcat + 768 * 256, 256, 0, u % 16, u / 16, g2, lds);
  } else if (t < 128) {
    int u = t - 112;
    tr_tile2(wo, 256, wcat, 1280, 0, u % 4, u / 4, nullptr, lds);
  } else {
    int u = t - 128;
    tr_tile2(w2, 256, wcat, 1280, 256, u % 4, u / 4, nullptr, lds);
  }
}

// ehead[i] f32 [256][16384] -> bheadT bf16 [16384][256] (into Sbuf).
__global__ __launch_bounds__(256) void tr_mat_kernel(const float* src,
                                                     unsigned short* dst) {
  __shared__ float lds[64][65];
  tr_tile2(src, 16384, dst, 256, 0, blockIdx.x, blockIdx.y, nullptr, lds);
}

// ---------------------------------------------------------------------------
// MFMA bf16 GEMM: C[1024 x N] = A[1024 x K] * B^T. 64x64 tiles, 4 waves x
// (2x2 16x16x32 frags). A bf16 [M,K]; B bf16 [N,K]. Optional z-batch.
//   A-frag A[m=lane&15][k=quad*8+j]; B-frag B[k=quad*8+j][n=lane&15]
//   C/D: col=lane&15, row=quad*4+reg
// ---------------------------------------------------------------------------
enum { EPI_FUSED1 = 0, EPI_ADD2, EPI_COND_F32, EPI_SCORES_BF16, EPI_PV_BF16 };

struct GemmArgs {
  const unsigned short* A; int lda; long long aStrideZ;
  const unsigned short* B; long long bOff; int ldb; long long bStrideZ;
  void* C; int ldc; long long cStrideZ;
  int K;
  const float* biasf;    // FUSED1: [1792] folded; ADD2: b2 (pre-offset)
  unsigned short* qkvb;  // FUSED1
  unsigned short* VT;    // FUSED1: [4][64][1024]
  unsigned short* af;    // FUSED1: hmid region of af[1024][1280]
  float* normsq;         // ADD2
  const int* exited;     // COND
  const int* guard;
  int causalK;           // PV: kLimit = bm + 64
  int xcdswz;            // XCD-contiguous block remap (grid blocks % 8 == 0)
};

template <int EPI>
__global__ __launch_bounds__(256) void gemm_mfma(GemmArgs g) {
  if (g.guard && *g.guard == 0) return;
  int bx = blockIdx.x, by = blockIdx.y;
  if (g.xcdswz) {
    int lin = bx + gridDim.x * by;
    int cpx = (gridDim.x * gridDim.y) >> 3;
    int s2 = (lin & 7) * cpx + (lin >> 3);  // bijective: blocks % 8 == 0
    bx = s2 % gridDim.x; by = s2 / gridDim.x;
  }
  const int bm = bx * 64;
  const int bn = by * 64;
  const int z = blockIdx.z;

  if constexpr (EPI == EPI_SCORES_BF16) {
    if (bn > bm) return;  // fully-masked tile: never read (softmax/PV clamp)
  }

  __shared__ __align__(16) unsigned short As[64][40];  // [m][k], 80B row
  __shared__ __align__(16) unsigned short Bs[64][40];  // [n][k]

  const int tid = threadIdx.x;
  const int lane = tid & 63;
  const int wave = tid >> 6;
  const int quad = lane >> 4, l16 = lane & 15;
  const int wr = (wave >> 1) * 32, wc = (wave & 1) * 32;
  const int rowA = tid >> 2, segA = (tid & 3) * 8;  // 64 rows x 32 k

  f32x4 acc[2][2] = {};
  const unsigned short* Az = g.A + (size_t)z * g.aStrideZ;
  const unsigned short* Bz = g.B + g.bOff + (size_t)z * g.bStrideZ;
  const int kLimit = g.causalK ? (bm + 64) : g.K;

  for (int k0 = 0; k0 < kLimit; k0 += 32) {
    *(ushort8*)&As[rowA][segA] =
        *(const ushort8*)(Az + (size_t)(bm + rowA) * g.lda + k0 + segA);
    *(ushort8*)&Bs[rowA][segA] =
        *(const ushort8*)(Bz + (size_t)(bn + rowA) * g.ldb + k0 + segA);
    __syncthreads();

    bf16x8 a0 = *(const bf16x8*)&As[wr + l16][quad * 8];
    bf16x8 a1 = *(const bf16x8*)&As[wr + 16 + l16][quad * 8];
    bf16x8 b0 = *(const bf16x8*)&Bs[wc + l16][quad * 8];
    bf16x8 b1 = *(const bf16x8*)&Bs[wc + 16 + l16][quad * 8];
    acc[0][0] = __builtin_amdgcn_mfma_f32_16x16x32_bf16(a0, b0, acc[0][0], 0, 0, 0);
    acc[0][1] = __builtin_amdgcn_mfma_f32_16x16x32_bf16(a0, b1, acc[0][1], 0, 0, 0);
    acc[1][0] = __builtin_amdgcn_mfma_f32_16x16x32_bf16(a1, b0, acc[1][0], 0, 0, 0);
    acc[1][1] = __builtin_amdgcn_mfma_f32_16x16x32_bf16(a1, b1, acc[1][1], 0, 0, 0);
    __syncthreads();
  }

  if constexpr (EPI == EPI_ADD2) {
    // dz = [O|hmid]@wcat^T + b2; fused per-row sum-of-squares
#pragma unroll
    for (int i2 = 0; i2 < 2; ++i2) {
#pragma unroll
      for (int r = 0; r < 4; ++r) {
        int row = bm + wr + i2 * 16 + quad * 4 + r;
        float sq = 0.f;
#pragma unroll
        for (int j = 0; j < 2; ++j) {
          int col = bn + wc + j * 16 + l16;
          float val = acc[i2][j][r] + g.biasf[col];
          ((float*)g.C)[(size_t)row * g.ldc + col] = val;
          sq += val * val;
        }
        sq += __shfl_xor(sq, 1); sq += __shfl_xor(sq, 2);
        sq += __shfl_xor(sq, 4); sq += __shfl_xor(sq, 8);
        if (l16 == 0) atomicAdd(g.normsq + row, sq);
      }
    }
    return;
  }

#pragma unroll
  for (int i = 0; i < 2; ++i) {
#pragma unroll
    for (int j = 0; j < 2; ++j) {
#pragma unroll
      for (int r = 0; r < 4; ++r) {
        int row = bm + wr + i * 16 + quad * 4 + r;
        int col = bn + wc + j * 16 + l16;
        float val = acc[i][j][r];
        if constexpr (EPI == EPI_FUSED1) {
          val += g.biasf[col];
          if (col < 768) {  // qkv (block-uniform: tile 64 | 768)
            unsigned short bv = f2bf(val);
            g.qkvb[(size_t)row * 768 + col] = bv;
            if (col >= 512) {  // V also transposed: VT[h][hd][tok]
              int cc = col - 512;
              g.VT[((cc >> 6) << 16) + ((cc & 63) << 10) + row] = bv;
            }
          } else {  // mlp mid: gelu -> af cols 256..1279
            g.af[(size_t)row * 1280 + 256 + (col - 768)] = f2bf(gelu_f(val));
          }
        } else if constexpr (EPI == EPI_SCORES_BF16) {
          float o = (col <= row) ? val * 0.125f : -1e9f;  // 1/sqrt(64) + causal
          ((unsigned short*)g.C)[(size_t)z * g.cStrideZ + (size_t)row * g.ldc + col] =
              f2bf(o);
        } else if constexpr (EPI == EPI_PV_BF16) {
          // O_h -> af cols z*64..z*64+63 (cStrideZ = 64)
          ((unsigned short*)g.C)[(size_t)z * g.cStrideZ + (size_t)row * g.ldc + col] =
              f2bf(val);
        } else if constexpr (EPI == EPI_COND_F32) {
          if (!g.exited[row])
            ((float*)g.C)[(size_t)row * g.ldc + col] = val;
        }
      }
    }
  }
}

// softmax in-place over bf16 rows of S[head][1024][1024], clamped to the
// causal prefix. Cols beyond rowEnd never read downstream (PV clamps K).
__global__ __launch_bounds__(256) void softmax_kernel(unsigned short* S,
                                                      const int* guard) {
  if (*guard == 0) return;
  int row = blockIdx.x, h = blockIdx.y;
  unsigned short* p = S + ((size_t)h << 20) + ((size_t)row << 10);
  int t = threadIdx.x, lane = t & 63, wave = t >> 6;
  int rowEnd = (row & ~63) + 64;
  bool act = (t * 4) < rowEnd;
  float v0 = -1e30f, v1 = -1e30f, v2 = -1e30f, v3 = -1e30f;
  if (act) {
    ushort4 u = ((ushort4*)p)[t];
    v0 = bf2f(u.x); v1 = bf2f(u.y); v2 = bf2f(u.z); v3 = bf2f(u.w);
  }
  float m = fmaxf(fmaxf(v0, v1), fmaxf(v2, v3));
#pragma unroll
  for (int o = 32; o; o >>= 1) m = fmaxf(m, __shfl_xor(m, o));
  __shared__ float red[4];
  if (lane == 0) red[wave] = m;
  __syncthreads();
  m = fmaxf(fmaxf(red[0], red[1]), fmaxf(red[2], red[3]));
  float e0 = expf(v0 - m), e1 = expf(v1 - m), e2 = expf(v2 - m), e3 = expf(v3 - m);
  float s = e0 + e1 + e2 + e3;
#pragma unroll
  for (int o = 32; o; o >>= 1) s += __shfl_xor(s, o);
  __syncthreads();
  if (lane == 0) red[wave] = s;
  __syncthreads();
  s = red[0] + red[1] + red[2] + red[3];
  float inv = 1.f / s;
  if (act) {
    ushort4 w; w.x = f2bf(e0 * inv); w.y = f2bf(e1 * inv);
    w.z = f2bf(e2 * inv); w.w = f2bf(e3 * inv);
    ((ushort4*)p)[t] = w;
  }
}

// ---------------------------------------------------------------------------
// Small kernels
// ---------------------------------------------------------------------------
__global__ void embed_kernel(const float* wte, const float* wpe, const int* idx,
                             float* z_prev, float* z_s, int* exited,
                             const int* i64f, Scalars* sc) {
  int tok = blockIdx.x, d = threadIdx.x;
  int id = (*i64f) ? idx[2 * tok] : idx[tok];
  float v = wte[(size_t)id * 256 + d] + wpe[(size_t)tok * 256 + d];
  z_prev[tok * 256 + d] = v;
  z_s[tok * 256 + d] = v;
  if (d == 0) exited[tok] = 0;
  if (tok == 0 && d == 0) {
    sc->active = 1; sc->step_active = 0; sc->t = 0.f; sc->steps = 0; sc->dt = 0.f;
  }
}

// Fused step head: apply pending Euler update, then plain layernorm (gamma/
// beta folded into weights) -> x_hat bf16. Also zeroes normsq.
__global__ void upln_kernel(float* z_s, const float* dz, unsigned short* xh,
                            float* normsq, const Scalars* sc) {
  const int sa = sc->step_active, act = sc->active;
  if (!sa && !act) return;
  int wave = threadIdx.x >> 6, lane = threadIdx.x & 63;
  int tok = blockIdx.x * 4 + wave;
  float* p = z_s + (size_t)tok * 256;
  float v[4];
#pragma unroll
  for (int j = 0; j < 4; ++j) v[j] = p[lane + 64 * j];
  if (sa) {
    float dt = sc->dt;
    const float* d = dz + (size_t)tok * 256;
#pragma unroll
    for (int j = 0; j < 4; ++j) {
      v[j] += dt * d[lane + 64 * j];
      p[lane + 64 * j] = v[j];
    }
  }
  if (!act) return;
  if (blockIdx.x == 0) {
#pragma unroll
    for (int j = 0; j < 4; ++j) normsq[threadIdx.x * 4 + j] = 0.f;
  }
  float s = 0.f, s2 = 0.f;
#pragma unroll
  for (int j = 0; j < 4; ++j) { s += v[j]; s2 += v[j] * v[j]; }
#pragma unroll
  for (int o = 1; o < 64; o <<= 1) { s += __shfl_xor(s, o); s2 += __shfl_xor(s2, o); }
  float mean = s * (1.f / 256.f);
  float var = s2 * (1.f / 256.f) - mean * mean;
  float rstd = rsqrtf(var + 1e-5f);
#pragma unroll
  for (int j = 0; j < 4; ++j) {
    int d = lane + 64 * j;
    xh[(size_t)tok * 256 + d] = f2bf((v[j] - mean) * rstd);
  }
}

// layernorm (exit-head): f32 in -> bf16 out, one wave per token
__global__ void ln_kernel(const float* x, const float* gg, const float* bb, int goff,
                          unsigned short* out) {
  int wave = threadIdx.x >> 6, lane = threadIdx.x & 63;
  int tok = blockIdx.x * 4 + wave;
  const float* p = x + (size_t)tok * 256;
  float v[4];
  float s = 0.f, s2 = 0.f;
#pragma unroll
  for (int j = 0; j < 4; ++j) { v[j] = p[lane + 64 * j]; s += v[j]; s2 += v[j] * v[j]; }
#pragma unroll
  for (int o = 1; o < 64; o <<= 1) { s += __shfl_xor(s, o); s2 += __shfl_xor(s2, o); }
  float mean = s * (1.f / 256.f);
  float var = s2 * (1.f / 256.f) - mean * mean;
  float rstd = rsqrtf(var + 1e-5f);
#pragma unroll
  for (int j = 0; j < 4; ++j) {
    int d = lane + 64 * j;
    out[(size_t)tok * 256 + d] = f2bf((v[j] - mean) * rstd * gg[goff + d] + bb[goff + d]);
  }
}

__global__ __launch_bounds__(1024) void scalar_kernel(const float* normsq, Scalars* sc) {
  __shared__ float red[1024];
  if (sc->active == 0) { if (threadIdx.x == 0) sc->step_active = 0; return; }
  int t = threadIdx.x;
  red[t] = sqrtf(normsq[t]);
  __syncthreads();
  for (int o = 512; o; o >>= 1) { if (t < o) red[t] += red[t + o]; __syncthreads(); }
  if (t == 0) {
    float mc = red[0] * (1.f / 1024.f);
    float scale = fminf(fmaxf(1.f / (1.f + mc), 0.5f), 2.f);
    float dt = fminf(0.5f * scale, 1.f - sc->t);  // dt_base = 1/MIN_STEPS
    sc->dt = dt;
    sc->step_active = 1;
    float tn = sc->t + dt;
    int steps = sc->steps + 1;
    sc->t = tn;
    sc->steps = steps;
    int conv = (dt * mc < 0.1f) && (steps >= 2);  // ||z_new-z|| = dt*||dz||
    sc->active = ((tn < 1.f - 1e-6f) && !conv) ? 1 : 0;
  }
}

// combine (z_prev += solver state, masked by exited) fused with next-layer
// solver-state init. Applies the final pending Euler update first.
__global__ void combine_init_kernel(float* z_prev, float* z_s, const float* dz,
                                    const int* exited, const Scalars* sc) {
  int i = blockIdx.x * 256 + threadIdx.x;
  int tok = i >> 6;
  float4 b = ((float4*)z_s)[i];
  if (sc->step_active) {
    float dt = sc->dt;
    float4 d = ((const float4*)dz)[i];
    b.x += dt * d.x; b.y += dt * d.y; b.z += dt * d.z; b.w += dt * d.w;
  }
  float4 a = ((float4*)z_prev)[i];
  if (!exited[tok]) {
    a.x += b.x; a.y += b.y; a.z += b.z; a.w += b.w;
    ((float4*)z_prev)[i] = a;
  }
  ((float4*)z_s)[i] = a;
}

__global__ __launch_bounds__(256) void conf_kernel(const float* logits, int* exited) {
  int tok = blockIdx.x;
  if (exited[tok]) return;
  const float* p = logits + ((size_t)tok << 14);
  int t = threadIdx.x, lane = t & 63, wave = t >> 6;
  float m = -1e30f;
  const float4* p4 = (const float4*)p;
  for (int j = t; j < 4096; j += 256) {
    float4 u = p4[j];
    m = fmaxf(fmaxf(fmaxf(m, u.x), u.y), fmaxf(u.z, u.w));
  }
#pragma unroll
  for (int o = 32; o; o >>= 1) m = fmaxf(m, __shfl_xor(m, o));
  __shared__ float red[4];
  if (lane == 0) red[wave] = m;
  __syncthreads();
  m = fmaxf(fmaxf(red[0], red[1]), fmaxf(red[2], red[3]));
  float s = 0.f;
  for (int j = t; j < 16384; j += 256) s += expf(p[j] - m);
#pragma unroll
  for (int o = 32; o; o >>= 1) s += __shfl_xor(s, o);
  __syncthreads();
  if (lane == 0) red[wave] = s;
  __syncthreads();
  s = red[0] + red[1] + red[2] + red[3];
  if (t == 0 && (1.f / s) > 0.9f) exited[tok] = 1;
}

// ---------------------------------------------------------------------------
// Host launch
// ---------------------------------------------------------------------------
extern "C" void kernel_launch(void* const* d_in, const int* in_sizes, int n_in,
                              void* d_out, int out_size, void* d_ws, size_t ws_size,
                              hipStream_t stream) {
  (void)out_size;
  const float* wte   = (const float*)d_in[0];
  const float* wpe   = (const float*)d_in[1];
  const float* ln1_g = (const float*)d_in[2];
  const float* ln1_b = (const float*)d_in[3];
  const float* wqkv  = (const float*)d_in[4];
  const float* wo    = (const float*)d_in[5];
  const float* ln2_g = (const float*)d_in[6];
  const float* ln2_b = (const float*)d_in[7];
  const float* w1    = (const float*)d_in[8];
  const float* b1    = (const float*)d_in[9];
  const float* w2    = (const float*)d_in[10];
  const float* b2    = (const float*)d_in[11];
  const float* eln_g = (const float*)d_in[12];
  const float* eln_b = (const float*)d_in[13];
  const float* ehead = (const float*)d_in[14];
  const int* idx = (const int*)d_in[15];
  float* out = (float*)d_out;  // f32 output

  float sentinel = 0.f;
  if (!(n_in == 16 && in_sizes[0] == 4194304 && in_sizes[14] == 16777216 &&
        in_sizes[15] == 1024))
    sentinel += 1000.f;
  if (ws_size < (size_t)20000000) sentinel += 2000.f;

  char* w = (char*)d_ws;
  auto alloc = [&](size_t bytes) {
    char* p = w; w += (bytes + 255) & ~(size_t)255; return p;
  };
  int* i64f        = (int*)alloc(256);
  Scalars* sc      = (Scalars*)alloc(sizeof(Scalars));
  int* exited      = (int*)alloc(1024 * 4);
  float* normsq    = (float*)alloc(1024 * 4);
  float* biasf     = (float*)alloc(1792 * 4);
  float* z_prev    = (float*)alloc(1024 * 256 * 4);
  float* z_s       = (float*)alloc(1024 * 256 * 4);
  float* dz        = (float*)alloc(1024 * 256 * 4);
  unsigned short* xh   = (unsigned short*)alloc(1024 * 256 * 2);
  unsigned short* zn   = (unsigned short*)alloc(1024 * 256 * 2);
  unsigned short* qkvb = (unsigned short*)alloc((size_t)1024 * 768 * 2);
  unsigned short* af   = (unsigned short*)alloc((size_t)1024 * 1280 * 2);  // [O|hmid]
  unsigned short* Sbuf = (unsigned short*)alloc((size_t)4 * 1024 * 1024 * 2);  // 8 MB (S / bheadT)
  unsigned short* bcat = (unsigned short*)alloc((size_t)1792 * 256 * 2);   // [qkvT;w1T]
  unsigned short* wcat = (unsigned short*)alloc((size_t)256 * 1280 * 2);   // [woT|w2T]
  unsigned short* VT   = (unsigned short*)alloc((size_t)4 * 64 * 1024 * 2);
  const int* guard = &sc->active;

  detect_idx_kernel<<<1, 256, 0, stream>>>(idx, i64f);
  embed_kernel<<<1024, 256, 0, stream>>>(wte, wpe, idx, z_prev, z_s, exited,
                                         i64f, sc);

  for (int i = 0; i < 4; ++i) {
    tr_weights_kernel<<<199, 256, 0, stream>>>(
        wqkv + (size_t)i * 196608, wo + (size_t)i * 65536,
        w1 + (size_t)i * 262144, w2 + (size_t)i * 262144,
        ln1_g + i * 256, ln1_b + i * 256, ln2_g + i * 256, ln2_b + i * 256,
        b1 + i * 1024, bcat, wcat, biasf, sc);
    for (int s = 0; s < 4; ++s) {
      upln_kernel<<<256, 256, 0, stream>>>(z_s, dz, xh, normsq, sc);
      {  // [qkv | gelu-mlp-mid] = xh @ bcat^T (+folded bias), N=1792
        GemmArgs a{}; a.A = xh; a.lda = 256;
        a.B = bcat; a.ldb = 256; a.K = 256;
        a.biasf = biasf; a.qkvb = qkvb; a.VT = VT; a.af = af; a.guard = guard;
        gemm_mfma<EPI_FUSED1><<<dim3(16, 28, 1), 256, 0, stream>>>(a);
      }
      {  // S_h = Q_h @ K_h^T * 0.125 causal -> bf16, batched over heads
        GemmArgs a{}; a.A = qkvb; a.lda = 768; a.aStrideZ = 64;
        a.B = qkvb; a.bOff = 256; a.ldb = 768; a.bStrideZ = 64;
        a.C = Sbuf; a.ldc = 1024; a.cStrideZ = 1048576; a.K = 64; a.guard = guard;
        gemm_mfma<EPI_SCORES_BF16><<<dim3(16, 16, 4), 256, 0, stream>>>(a);
      }
      softmax_kernel<<<dim3(1024, 4), 256, 0, stream>>>(Sbuf, guard);
      {  // O_h = P_h @ V_h -> af cols h*64.. ; causal K clamp
        GemmArgs a{}; a.A = Sbuf; a.lda = 1024; a.aStrideZ = 1048576;
        a.B = VT; a.ldb = 1024; a.bStrideZ = 65536;
        a.C = af; a.ldc = 1280; a.cStrideZ = 64; a.K = 1024; a.causalK = 1;
        a.guard = guard;
        gemm_mfma<EPI_PV_BF16><<<dim3(16, 1, 4), 256, 0, stream>>>(a);
      }
      {  // dz = [O|hmid] @ wcat^T + b2; fused row-norm accumulation
        GemmArgs a{}; a.A = af; a.lda = 1280;
        a.B = wcat; a.ldb = 1280;
        a.C = dz; a.ldc = 256; a.K = 1280;
        a.biasf = b2 + i * 256; a.normsq = normsq; a.guard = guard;
        gemm_mfma<EPI_ADD2><<<dim3(16, 4, 1), 256, 0, stream>>>(a);
      }
      scalar_kernel<<<1, 1024, 0, stream>>>(normsq, sc);
    }
    combine_init_kernel<<<256, 256, 0, stream>>>(z_prev, z_s, dz, exited, sc);
    // Layer 0 logits are provably dead (exited all-false until after layer-1
    // conf -> layer 1 overwrites every row). i=3 conf mutates dead state.
    if (i >= 1) {
      ln_kernel<<<256, 256, 0, stream>>>(z_prev, eln_g, eln_b, i * 256, zn);
      tr_mat_kernel<<<dim3(256, 4), 256, 0, stream>>>(
          ehead + (size_t)i * 4194304, Sbuf);
      {  // blk_logits = zn @ bheadT -> d_out (f32) where !exited
        GemmArgs a{}; a.A = zn; a.lda = 256;
        a.B = Sbuf; a.ldb = 256;
        a.C = out; a.ldc = 16384; a.K = 256; a.exited = exited; a.xcdswz = 1;
        gemm_mfma<EPI_COND_F32><<<dim3(16, 256, 1), 256, 0, stream>>>(a);
      }
      if (i < 3) conf_kernel<<<1024, 256, 0, stream>>>(out, exited);
    }
  }

  sentinel_kernel<<<1, 1, 0, stream>>>(out, sentinel);
}

// Round 6
// 1355.291 us; speedup vs baseline: 1.5009x; 1.1080x over previous
//
#include <hip/hip_runtime.h>
#include <stdint.h>

typedef __bf16 bf16x8 __attribute__((ext_vector_type(8)));
typedef float f32x4 __attribute__((ext_vector_type(4)));
typedef unsigned short ushort8 __attribute__((ext_vector_type(8)));

#define DEV static __device__ __forceinline__

DEV float bf2f(unsigned short h) {
  union { unsigned u; float f; } v; v.u = ((unsigned)h) << 16; return v.f;
}
DEV unsigned short f2bf(float f) {
  union { float f; unsigned u; } v; v.f = f;
  unsigned r = v.u + 0x7fffu + ((v.u >> 16) & 1u);  // RNE
  return (unsigned short)(r >> 16);
}
DEV float gelu_f(float x) {  // jax.nn.gelu approximate=True (tanh)
  const float c = 0.7978845608028654f;
  return 0.5f * x * (1.f + tanhf(c * (x + 0.044715f * x * x * x)));
}

struct Scalars { int active; int step_active; int steps; float t; float dt; };

// idx width probe (int64 -> (id,0,id,0,...) viewed as int32). Proven harmless.
__global__ void detect_idx_kernel(const int* idx, int* i64f) {
  __shared__ int anyOdd, anyEven;
  if (threadIdx.x == 0) { anyOdd = 0; anyEven = 0; }
  __syncthreads();
  for (int j = threadIdx.x; j < 1024; j += 256) {
    int v = idx[j];
    if (j & 1) { if (v != 0) anyOdd = 1; }
    else       { if (v != 0) anyEven = 1; }
  }
  __syncthreads();
  if (threadIdx.x == 0) *i64f = (anyOdd == 0 && anyEven == 1) ? 1 : 0;
}

__global__ void sentinel_kernel(float* out, float val) {
  if (val != 0.f) out[0] = val;
}

// ---------------------------------------------------------------------------
// Transpose-convert: src f32, tile [ty*64..][tx*64..] of [R][C] row-major
// -> dst bf16 [n=tx*64+..][kOff + ty*64+..], optional per-k scale g[k].
// ---------------------------------------------------------------------------
DEV void tr_tile2(const float* src, int ldS, unsigned short* dst, int ldD,
                  int kOff, int tx, int ty, const float* gsc, float (*lds)[65]) {
  const int tid = threadIdx.x;
#pragma unroll
  for (int jj = 0; jj < 4; ++jj) {
    int r = jj * 16 + (tid >> 4);
    int c = (tid & 15) * 4;
    float4 v = *(const float4*)&src[(size_t)(ty * 64 + r) * ldS + tx * 64 + c];
    lds[r][c] = v.x; lds[r][c + 1] = v.y; lds[r][c + 2] = v.z; lds[r][c + 3] = v.w;
  }
  __syncthreads();
  const int lr = tid >> 2, seg = (tid & 3) * 16;
  ushort8 o0, o1;
#pragma unroll
  for (int e = 0; e < 8; ++e) {
    float gs = gsc ? gsc[ty * 64 + seg + e] : 1.f;
    o0[e] = f2bf(lds[seg + e][lr] * gs);
  }
#pragma unroll
  for (int e = 0; e < 8; ++e) {
    float gs = gsc ? gsc[ty * 64 + seg + 8 + e] : 1.f;
    o1[e] = f2bf(lds[seg + 8 + e][lr] * gs);
  }
  unsigned short* dp = dst + (size_t)(tx * 64 + lr) * ldD + kOff + ty * 64 + seg;
  *(ushort8*)dp = o0;
  *(ushort8*)(dp + 8) = o1;
}

// Per-layer weight prep (199 blocks); block 0 resets scarr[0] (ODE init).
__global__ __launch_bounds__(256) void tr_weights_kernel(
    const float* wqkv, const float* wo, const float* w1, const float* w2,
    const float* g1, const float* b1ln, const float* g2, const float* b2ln,
    const float* b1mlp, unsigned short* bcat, unsigned short* wcat,
    float* biasf, Scalars* sc0) {
  int t = blockIdx.x;
  if (t == 0 && threadIdx.x == 0) {
    sc0->active = 1; sc0->step_active = 0; sc0->t = 0.f; sc0->steps = 0; sc0->dt = 0.f;
  }
  if (t >= 192) {
    int n = (t - 192) * 256 + threadIdx.x;  // 0..1791
    float acc = 0.f;
    if (n < 768) {
      for (int k = 0; k < 256; ++k) acc += b1ln[k] * wqkv[(size_t)k * 768 + n];
    } else {
      int mc = n - 768;
      acc = b1mlp[mc];
      for (int k = 0; k < 256; ++k) acc += b2ln[k] * w1[(size_t)k * 1024 + mc];
    }
    biasf[n] = acc;
    return;
  }
  __shared__ float lds[64][65];
  if (t < 48) {
    tr_tile2(wqkv, 768, bcat, 256, 0, t % 12, t / 12, g1, lds);
  } else if (t < 112) {
    int u = t - 48;
    tr_tile2(w1, 1024, bcat + 768 * 256, 256, 0, u % 16, u / 16, g2, lds);
  } else if (t < 128) {
    int u = t - 112;
    tr_tile2(wo, 256, wcat, 1280, 0, u % 4, u / 4, nullptr, lds);
  } else {
    int u = t - 128;
    tr_tile2(w2, 256, wcat, 1280, 256, u % 4, u / 4, nullptr, lds);
  }
}

// ehead[i] f32 [256][16384] -> bheadT bf16 [16384][256] (into Sbuf).
__global__ __launch_bounds__(256) void tr_mat_kernel(const float* src,
                                                     unsigned short* dst) {
  __shared__ float lds[64][65];
  tr_tile2(src, 16384, dst, 256, 0, blockIdx.x, blockIdx.y, nullptr, lds);
}

// ---------------------------------------------------------------------------
// MFMA bf16 GEMM: C[1024 x N] = A[1024 x K] * B^T. 64x64 tiles, 4 waves x
// (2x2 16x16x32 frags). A bf16 [M,K]; B bf16 [N,K].
// ---------------------------------------------------------------------------
enum { EPI_FUSED1 = 0, EPI_ADD2, EPI_COND_F32 };

struct GemmArgs {
  const unsigned short* A; int lda;
  const unsigned short* B; int ldb;
  void* C; int ldc;
  int K;
  const float* biasf;    // FUSED1: [1792] folded; ADD2: b2 (pre-offset)
  unsigned short* qkvb;  // FUSED1
  unsigned short* VT;    // FUSED1: [4][64][1024]
  unsigned short* af;    // FUSED1: hmid region of af[1024][1280]
  float* normsq;         // ADD2 (parity buffer)
  const int* exited;     // COND
  const int* guard;
  int xcdswz;
};

template <int EPI>
__global__ __launch_bounds__(256) void gemm_mfma(GemmArgs g) {
  if (g.guard && *g.guard == 0) return;
  int bx = blockIdx.x, by = blockIdx.y;
  if (g.xcdswz) {
    int lin = bx + gridDim.x * by;
    int cpx = (gridDim.x * gridDim.y) >> 3;
    int s2 = (lin & 7) * cpx + (lin >> 3);  // bijective: blocks % 8 == 0
    bx = s2 % gridDim.x; by = s2 / gridDim.x;
  }
  const int bm = bx * 64;
  const int bn = by * 64;

  __shared__ __align__(16) unsigned short As[64][40];
  __shared__ __align__(16) unsigned short Bs[64][40];

  const int tid = threadIdx.x;
  const int lane = tid & 63;
  const int wave = tid >> 6;
  const int quad = lane >> 4, l16 = lane & 15;
  const int wr = (wave >> 1) * 32, wc = (wave & 1) * 32;
  const int rowA = tid >> 2, segA = (tid & 3) * 8;

  f32x4 acc[2][2] = {};

  for (int k0 = 0; k0 < g.K; k0 += 32) {
    *(ushort8*)&As[rowA][segA] =
        *(const ushort8*)(g.A + (size_t)(bm + rowA) * g.lda + k0 + segA);
    *(ushort8*)&Bs[rowA][segA] =
        *(const ushort8*)(g.B + (size_t)(bn + rowA) * g.ldb + k0 + segA);
    __syncthreads();

    bf16x8 a0 = *(const bf16x8*)&As[wr + l16][quad * 8];
    bf16x8 a1 = *(const bf16x8*)&As[wr + 16 + l16][quad * 8];
    bf16x8 b0 = *(const bf16x8*)&Bs[wc + l16][quad * 8];
    bf16x8 b1 = *(const bf16x8*)&Bs[wc + 16 + l16][quad * 8];
    acc[0][0] = __builtin_amdgcn_mfma_f32_16x16x32_bf16(a0, b0, acc[0][0], 0, 0, 0);
    acc[0][1] = __builtin_amdgcn_mfma_f32_16x16x32_bf16(a0, b1, acc[0][1], 0, 0, 0);
    acc[1][0] = __builtin_amdgcn_mfma_f32_16x16x32_bf16(a1, b0, acc[1][0], 0, 0, 0);
    acc[1][1] = __builtin_amdgcn_mfma_f32_16x16x32_bf16(a1, b1, acc[1][1], 0, 0, 0);
    __syncthreads();
  }

  if constexpr (EPI == EPI_ADD2) {
#pragma unroll
    for (int i2 = 0; i2 < 2; ++i2) {
#pragma unroll
      for (int r = 0; r < 4; ++r) {
        int row = bm + wr + i2 * 16 + quad * 4 + r;
        float sq = 0.f;
#pragma unroll
        for (int j = 0; j < 2; ++j) {
          int col = bn + wc + j * 16 + l16;
          float val = acc[i2][j][r] + g.biasf[col];
          ((float*)g.C)[(size_t)row * g.ldc + col] = val;
          sq += val * val;
        }
        sq += __shfl_xor(sq, 1); sq += __shfl_xor(sq, 2);
        sq += __shfl_xor(sq, 4); sq += __shfl_xor(sq, 8);
        if (l16 == 0) atomicAdd(g.normsq + row, sq);
      }
    }
    return;
  }

#pragma unroll
  for (int i = 0; i < 2; ++i) {
#pragma unroll
    for (int j = 0; j < 2; ++j) {
#pragma unroll
      for (int r = 0; r < 4; ++r) {
        int row = bm + wr + i * 16 + quad * 4 + r;
        int col = bn + wc + j * 16 + l16;
        float val = acc[i][j][r];
        if constexpr (EPI == EPI_FUSED1) {
          val += g.biasf[col];
          if (col < 768) {  // qkv (block-uniform: tile 64 | 768)
            unsigned short bv = f2bf(val);
            g.qkvb[(size_t)row * 768 + col] = bv;
            if (col >= 512) {  // V also transposed: VT[h][hd][tok]
              int cc = col - 512;
              g.VT[((cc >> 6) << 16) + ((cc & 63) << 10) + row] = bv;
            }
          } else {  // mlp mid: gelu -> af cols 256..1279
            g.af[(size_t)row * 1280 + 256 + (col - 768)] = f2bf(gelu_f(val));
          }
        } else if constexpr (EPI == EPI_COND_F32) {
          if (!g.exited[row])
            ((float*)g.C)[(size_t)row * g.ldc + col] = val;
        }
      }
    }
  }
}

// ---------------------------------------------------------------------------
// Fused attention, parallelism-preserving: one block per (16-row Q-tile, head)
// = 256 blocks. S band LDS-resident (no global round trips). Phase 1 and 3
// reproduce the previous scores/PV GEMMs' MFMA order bit-for-bit; phase 2
// softmax matches the old element partitioning (sum association differs by
// wave-vs-4-wave tree only -> ulp noise).
// ---------------------------------------------------------------------------
__global__ __launch_bounds__(256) void attn_kernel(
    const unsigned short* qkvb, const unsigned short* VT,
    unsigned short* af, const int* guard) {
  if (*guard == 0) return;
  const int qt = blockIdx.x;          // 16-row tile, 0..63
  const int h = blockIdx.y;
  const int nkt = (qt >> 2) + 1;      // causal 64-col band count
  __shared__ __align__(16) unsigned short S[16][1064];  // pad: stride 532 words
  __shared__ __align__(16) unsigned short KV[64][88];
  const int tid = threadIdx.x, lane = tid & 63, wave = tid >> 6;
  const int quad = lane >> 4, l16 = lane & 15;
  const int srow = tid >> 3, scol = (tid & 7) * 8;

  // Q A-frags direct from global (all waves identical; L1/L2-served)
  bf16x8 aq[2];
  {
    const unsigned short* Qp =
        qkvb + (size_t)(qt * 16 + l16) * 768 + h * 64 + quad * 8;
    aq[0] = *(const bf16x8*)Qp;
    aq[1] = *(const bf16x8*)(Qp + 32);
  }

  // ---- phase 1: S = Q@K^T * 0.125, causal mask, bf16 -> LDS
  for (int kt = 0; kt < nkt; ++kt) {
    const unsigned short* Kp = qkvb + (size_t)(kt * 64) * 768 + 256 + h * 64;
#pragma unroll
    for (int hh = 0; hh < 2; ++hh)
      *(ushort8*)&KV[hh * 32 + srow][scol] =
          *(const ushort8*)(Kp + (size_t)(hh * 32 + srow) * 768 + scol);
    __syncthreads();
    f32x4 sa = {};
#pragma unroll
    for (int k0 = 0; k0 < 2; ++k0) {
      bf16x8 b = *(const bf16x8*)&KV[wave * 16 + l16][k0 * 32 + quad * 8];
      sa = __builtin_amdgcn_mfma_f32_16x16x32_bf16(aq[k0], b, sa, 0, 0, 0);
    }
#pragma unroll
    for (int r = 0; r < 4; ++r) {
      int rowg = qt * 16 + quad * 4 + r;
      int colg = kt * 64 + wave * 16 + l16;
      float o = (colg <= rowg) ? sa[r] * 0.125f : -1e9f;
      S[quad * 4 + r][kt * 64 + wave * 16 + l16] = f2bf(o);
    }
    __syncthreads();
  }

  // ---- phase 2: softmax rows in LDS (wave per row)
  const int rowEnd = nkt * 64;
#pragma unroll
  for (int it = 0; it < 4; ++it) {
    int r = it * 4 + wave;
    unsigned short* p = &S[r][0];
    float v[16];
    float m = -1e30f;
#pragma unroll
    for (int ps = 0; ps < 4; ++ps) {
      int c = ps * 256 + lane * 4;
      if (c < rowEnd) {
        ushort4 u = *(const ushort4*)(p + c);
        v[ps * 4 + 0] = bf2f(u.x); v[ps * 4 + 1] = bf2f(u.y);
        v[ps * 4 + 2] = bf2f(u.z); v[ps * 4 + 3] = bf2f(u.w);
      } else {
        v[ps * 4 + 0] = v[ps * 4 + 1] = v[ps * 4 + 2] = v[ps * 4 + 3] = -1e30f;
      }
      m = fmaxf(m, fmaxf(fmaxf(v[ps * 4], v[ps * 4 + 1]),
                         fmaxf(v[ps * 4 + 2], v[ps * 4 + 3])));
    }
#pragma unroll
    for (int o = 32; o; o >>= 1) m = fmaxf(m, __shfl_xor(m, o));
    float s = 0.f;
#pragma unroll
    for (int e = 0; e < 16; ++e) { v[e] = expf(v[e] - m); s += v[e]; }
#pragma unroll
    for (int o = 32; o; o >>= 1) s += __shfl_xor(s, o);
    float inv = 1.f / s;
#pragma unroll
    for (int ps = 0; ps < 4; ++ps) {
      int c = ps * 256 + lane * 4;
      if (c < rowEnd) {
        ushort4 w4;
        w4.x = f2bf(v[ps * 4 + 0] * inv); w4.y = f2bf(v[ps * 4 + 1] * inv);
        w4.z = f2bf(v[ps * 4 + 2] * inv); w4.w = f2bf(v[ps * 4 + 3] * inv);
        *(ushort4*)(p + c) = w4;
      }
    }
  }
  __syncthreads();

  // ---- phase 3: O = P@V -> af cols h*64.. (ascending k, matches old PV)
  f32x4 ao = {};
  for (int kt = 0; kt < nkt; ++kt) {
    const unsigned short* Vp = VT + ((size_t)h << 16) + kt * 64;
#pragma unroll
    for (int hh = 0; hh < 2; ++hh)
      *(ushort8*)&KV[hh * 32 + srow][scol] =
          *(const ushort8*)(Vp + (size_t)(hh * 32 + srow) * 1024 + scol);
    __syncthreads();
#pragma unroll
    for (int k0 = 0; k0 < 2; ++k0) {
      bf16x8 pa = *(const bf16x8*)&S[l16][kt * 64 + k0 * 32 + quad * 8];
      bf16x8 b = *(const bf16x8*)&KV[wave * 16 + l16][k0 * 32 + quad * 8];
      ao = __builtin_amdgcn_mfma_f32_16x16x32_bf16(pa, b, ao, 0, 0, 0);
    }
    __syncthreads();
  }
#pragma unroll
  for (int r = 0; r < 4; ++r) {
    int rowg = qt * 16 + quad * 4 + r;
    int colg = h * 64 + wave * 16 + l16;
    af[(size_t)rowg * 1280 + colg] = f2bf(ao[r]);
  }
}

// ---------------------------------------------------------------------------
// Small kernels
// ---------------------------------------------------------------------------
__global__ void embed_kernel(const float* wte, const float* wpe, const int* idx,
                             float* z_prev, float* z_s, int* exited,
                             const int* i64f) {
  int tok = blockIdx.x, d = threadIdx.x;
  int id = (*i64f) ? idx[2 * tok] : idx[tok];
  float v = wte[(size_t)id * 256 + d] + wpe[(size_t)tok * 256 + d];
  z_prev[tok * 256 + d] = v;
  z_s[tok * 256 + d] = v;
  if (d == 0) exited[tok] = 0;
}

// Fused step head: recompute previous step's scalar update (redundant per
// block, bit-identical tree) -> apply pending Euler update -> layernorm ->
// x_hat bf16. Zeroes this step's normsq parity buffer.
__global__ __launch_bounds__(256) void upln_kernel(
    float* z_s, const float* dz, unsigned short* xh,
    const float* nsq_read, float* nsq_zero,
    const Scalars* sc_prev, Scalars* sc_out, int first) {
  __shared__ float red[256];
  __shared__ Scalars stsh;
  const int tid = threadIdx.x;
  float v = 0.f;
  if (!first) {
    v = (sqrtf(nsq_read[tid]) + sqrtf(nsq_read[tid + 512])) +
        (sqrtf(nsq_read[tid + 256]) + sqrtf(nsq_read[tid + 768]));
  }
  red[tid] = v;
  __syncthreads();
  for (int o = 128; o; o >>= 1) {
    if (tid < o) red[tid] += red[tid + o];
    __syncthreads();
  }
  if (tid == 0) {
    Scalars st = *sc_prev;
    if (!first) {
      if (!st.active) {
        st.step_active = 0;
      } else {
        float mc = red[0] * (1.f / 1024.f);
        float scale = fminf(fmaxf(1.f / (1.f + mc), 0.5f), 2.f);
        float dt = fminf(0.5f * scale, 1.f - st.t);
        st.dt = dt; st.step_active = 1;
        float tn = st.t + dt;
        int steps = st.steps + 1;
        st.t = tn; st.steps = steps;
        int conv = (dt * mc < 0.1f) && (steps >= 2);
        st.active = ((tn < 1.f - 1e-6f) && !conv) ? 1 : 0;
      }
    }
    stsh = st;
    if (blockIdx.x == 0) *sc_out = st;
  }
  __syncthreads();
  const Scalars st = stsh;
  if (blockIdx.x == 0) {
#pragma unroll
    for (int j = 0; j < 4; ++j) nsq_zero[tid * 4 + j] = 0.f;
  }
  if (!st.step_active && !st.active) return;

  int wave = tid >> 6, lane = tid & 63;
  int tok = blockIdx.x * 4 + wave;
  float* p = z_s + (size_t)tok * 256;
  float vv[4];
#pragma unroll
  for (int j = 0; j < 4; ++j) vv[j] = p[lane + 64 * j];
  if (st.step_active) {
    float dt = st.dt;
    const float* d = dz + (size_t)tok * 256;
#pragma unroll
    for (int j = 0; j < 4; ++j) {
      vv[j] += dt * d[lane + 64 * j];
      p[lane + 64 * j] = vv[j];
    }
  }
  if (!st.active) return;
  float s = 0.f, s2 = 0.f;
#pragma unroll
  for (int j = 0; j < 4; ++j) { s += vv[j]; s2 += vv[j] * vv[j]; }
#pragma unroll
  for (int o = 1; o < 64; o <<= 1) { s += __shfl_xor(s, o); s2 += __shfl_xor(s2, o); }
  float mean = s * (1.f / 256.f);
  float var = s2 * (1.f / 256.f) - mean * mean;
  float rstd = rsqrtf(var + 1e-5f);
#pragma unroll
  for (int j = 0; j < 4; ++j) {
    int d = lane + 64 * j;
    xh[(size_t)tok * 256 + d] = f2bf((vv[j] - mean) * rstd);
  }
}

// combine (z_prev += solver state, masked) + final pending update (recomputed
// scalar) + next-layer z_s init + fused exit-head layernorm (doLN).
__global__ __launch_bounds__(256) void combine_init_kernel(
    float* z_prev, float* z_s, const float* dz, const int* exited,
    const Scalars* sc_prev, const float* nsq,
    const float* eg, const float* eb, int goff, unsigned short* zn, int doLN) {
  __shared__ float red[256];
  __shared__ float dtsh;
  __shared__ int sash;
  const int tid = threadIdx.x;
  float v = (sqrtf(nsq[tid]) + sqrtf(nsq[tid + 512])) +
            (sqrtf(nsq[tid + 256]) + sqrtf(nsq[tid + 768]));
  red[tid] = v;
  __syncthreads();
  for (int o = 128; o; o >>= 1) {
    if (tid < o) red[tid] += red[tid + o];
    __syncthreads();
  }
  if (tid == 0) {
    Scalars st = *sc_prev;
    int sa = 0; float dt = 0.f;
    if (st.active) {
      float mc = red[0] * (1.f / 1024.f);
      float scale = fminf(fmaxf(1.f / (1.f + mc), 0.5f), 2.f);
      dt = fminf(0.5f * scale, 1.f - st.t);
      sa = 1;
    }
    dtsh = dt; sash = sa;
  }
  __syncthreads();
  const int sa = sash;
  const float dt = dtsh;
  const int wave = tid >> 6, lane = tid & 63;
  const int tok = blockIdx.x * 4 + wave;
  const int ex = exited[tok];
  float a[4];
#pragma unroll
  for (int j = 0; j < 4; ++j) {
    int d = lane + 64 * j;
    float b = z_s[(size_t)tok * 256 + d];
    if (sa) b += dt * dz[(size_t)tok * 256 + d];
    float ap = z_prev[(size_t)tok * 256 + d];
    float an = ex ? ap : (ap + b);
    a[j] = an;
    if (!ex) z_prev[(size_t)tok * 256 + d] = an;
    z_s[(size_t)tok * 256 + d] = an;
  }
  if (!doLN) return;
  float s = 0.f, s2 = 0.f;
#pragma unroll
  for (int j = 0; j < 4; ++j) { s += a[j]; s2 += a[j] * a[j]; }
#pragma unroll
  for (int o = 1; o < 64; o <<= 1) { s += __shfl_xor(s, o); s2 += __shfl_xor(s2, o); }
  float mean = s * (1.f / 256.f);
  float var = s2 * (1.f / 256.f) - mean * mean;
  float rstd = rsqrtf(var + 1e-5f);
#pragma unroll
  for (int j = 0; j < 4; ++j) {
    int d = lane + 64 * j;
    zn[(size_t)tok * 256 + d] = f2bf((a[j] - mean) * rstd * eg[goff + d] + eb[goff + d]);
  }
}

__global__ __launch_bounds__(256) void conf_kernel(const float* logits, int* exited) {
  int tok = blockIdx.x;
  if (exited[tok]) return;
  const float* p = logits + ((size_t)tok << 14);
  int t = threadIdx.x, lane = t & 63, wave = t >> 6;
  float m = -1e30f;
  const float4* p4 = (const float4*)p;
  for (int j = t; j < 4096; j += 256) {
    float4 u = p4[j];
    m = fmaxf(fmaxf(fmaxf(m, u.x), u.y), fmaxf(u.z, u.w));
  }
#pragma unroll
  for (int o = 32; o; o >>= 1) m = fmaxf(m, __shfl_xor(m, o));
  __shared__ float red[4];
  if (lane == 0) red[wave] = m;
  __syncthreads();
  m = fmaxf(fmaxf(red[0], red[1]), fmaxf(red[2], red[3]));
  float s = 0.f;
  for (int j = t; j < 16384; j += 256) s += expf(p[j] - m);
#pragma unroll
  for (int o = 32; o; o >>= 1) s += __shfl_xor(s, o);
  __syncthreads();
  if (lane == 0) red[wave] = s;
  __syncthreads();
  s = red[0] + red[1] + red[2] + red[3];
  if (t == 0 && (1.f / s) > 0.9f) exited[tok] = 1;
}

// ---------------------------------------------------------------------------
// Host launch
// ---------------------------------------------------------------------------
extern "C" void kernel_launch(void* const* d_in, const int* in_sizes, int n_in,
                              void* d_out, int out_size, void* d_ws, size_t ws_size,
                              hipStream_t stream) {
  (void)out_size;
  const float* wte   = (const float*)d_in[0];
  const float* wpe   = (const float*)d_in[1];
  const float* ln1_g = (const float*)d_in[2];
  const float* ln1_b = (const float*)d_in[3];
  const float* wqkv  = (const float*)d_in[4];
  const float* wo    = (const float*)d_in[5];
  const float* ln2_g = (const float*)d_in[6];
  const float* ln2_b = (const float*)d_in[7];
  const float* w1    = (const float*)d_in[8];
  const float* b1    = (const float*)d_in[9];
  const float* w2    = (const float*)d_in[10];
  const float* b2    = (const float*)d_in[11];
  const float* eln_g = (const float*)d_in[12];
  const float* eln_b = (const float*)d_in[13];
  const float* ehead = (const float*)d_in[14];
  const int* idx = (const int*)d_in[15];
  float* out = (float*)d_out;

  float sentinel = 0.f;
  if (!(n_in == 16 && in_sizes[0] == 4194304 && in_sizes[14] == 16777216 &&
        in_sizes[15] == 1024))
    sentinel += 1000.f;
  if (ws_size < (size_t)20000000) sentinel += 2000.f;

  char* w = (char*)d_ws;
  auto alloc = [&](size_t bytes) {
    char* p = w; w += (bytes + 255) & ~(size_t)255; return p;
  };
  int* i64f        = (int*)alloc(256);
  Scalars* scarr   = (Scalars*)alloc(4 * sizeof(Scalars));  // per-step states
  int* exited      = (int*)alloc(1024 * 4);
  float* nsq       = (float*)alloc(2 * 1024 * 4);  // parity-double-buffered
  float* biasf     = (float*)alloc(1792 * 4);
  float* z_prev    = (float*)alloc(1024 * 256 * 4);
  float* z_s       = (float*)alloc(1024 * 256 * 4);
  float* dz        = (float*)alloc(1024 * 256 * 4);
  unsigned short* xh   = (unsigned short*)alloc(1024 * 256 * 2);
  unsigned short* zn   = (unsigned short*)alloc(1024 * 256 * 2);
  unsigned short* qkvb = (unsigned short*)alloc((size_t)1024 * 768 * 2);
  unsigned short* af   = (unsigned short*)alloc((size_t)1024 * 1280 * 2);  // [O|hmid]
  unsigned short* Sbuf = (unsigned short*)alloc((size_t)4 * 1024 * 1024 * 2);  // bheadT
  unsigned short* bcat = (unsigned short*)alloc((size_t)1792 * 256 * 2);
  unsigned short* wcat = (unsigned short*)alloc((size_t)256 * 1280 * 2);
  unsigned short* VT   = (unsigned short*)alloc((size_t)4 * 64 * 1024 * 2);

  detect_idx_kernel<<<1, 256, 0, stream>>>(idx, i64f);
  embed_kernel<<<1024, 256, 0, stream>>>(wte, wpe, idx, z_prev, z_s, exited, i64f);

  for (int i = 0; i < 4; ++i) {
    tr_weights_kernel<<<199, 256, 0, stream>>>(
        wqkv + (size_t)i * 196608, wo + (size_t)i * 65536,
        w1 + (size_t)i * 262144, w2 + (size_t)i * 262144,
        ln1_g + i * 256, ln1_b + i * 256, ln2_g + i * 256, ln2_b + i * 256,
        b1 + i * 1024, bcat, wcat, biasf, scarr);  // scarr[0] = init
    for (int s = 0; s < 4; ++s) {
      const int* guard = &scarr[s].active;
      // fused: scalar recompute + Euler update + LN + normsq zero
      upln_kernel<<<256, 256, 0, stream>>>(
          z_s, dz, xh, nsq + (((s + 1) & 1) << 10), nsq + ((s & 1) << 10),
          scarr + (s == 0 ? 0 : s - 1), scarr + s, s == 0 ? 1 : 0);
      {  // [qkv | gelu-mlp-mid] = xh @ bcat^T (+folded bias), N=1792
        GemmArgs a{}; a.A = xh; a.lda = 256;
        a.B = bcat; a.ldb = 256; a.K = 256;
        a.biasf = biasf; a.qkvb = qkvb; a.VT = VT; a.af = af; a.guard = guard;
        gemm_mfma<EPI_FUSED1><<<dim3(16, 28, 1), 256, 0, stream>>>(a);
      }
      // fused attention (S in LDS, 256 blocks)
      attn_kernel<<<dim3(64, 4), 256, 0, stream>>>(qkvb, VT, af, guard);
      {  // dz = [O|hmid] @ wcat^T + b2; fused row-norm accumulation
        GemmArgs a{}; a.A = af; a.lda = 1280;
        a.B = wcat; a.ldb = 1280;
        a.C = dz; a.ldc = 256; a.K = 1280;
        a.biasf = b2 + i * 256; a.normsq = nsq + ((s & 1) << 10); a.guard = guard;
        gemm_mfma<EPI_ADD2><<<dim3(16, 4, 1), 256, 0, stream>>>(a);
      }
    }
    // combine + final pending update (recomputed) + next init + exit LN
    combine_init_kernel<<<256, 256, 0, stream>>>(
        z_prev, z_s, dz, exited, scarr + 3, nsq + 1024,
        eln_g, eln_b, i * 256, zn, i >= 1 ? 1 : 0);
    if (i >= 1) {
      tr_mat_kernel<<<dim3(256, 4), 256, 0, stream>>>(
          ehead + (size_t)i * 4194304, Sbuf);
      {  // blk_logits = zn @ bheadT -> d_out (f32) where !exited
        GemmArgs a{}; a.A = zn; a.lda = 256;
        a.B = Sbuf; a.ldb = 256;
        a.C = out; a.ldc = 16384; a.K = 256; a.exited = exited; a.xcdswz = 1;
        gemm_mfma<EPI_COND_F32><<<dim3(16, 256, 1), 256, 0, stream>>>(a);
      }
      if (i < 3) conf_kernel<<<1024, 256, 0, stream>>>(out, exited);
    }
  }

  sentinel_kernel<<<1, 1, 0, stream>>>(out, sentinel);
}